// Round 7
// baseline (12351.649 us; speedup 1.0000x reference)
//
#include <hip/hip_runtime.h>
#include <hip/hip_bf16.h>
#include <math.h>

#define NN 16000
#define NE 256000
#define H 192
#define NHEAD 4
#define CC 48
#define NL 4
#define NBATCH 8
#define VEt 8
#define HH (H*H)

// monotone float<->uint mapping for atomicMax on signed floats
__device__ __forceinline__ unsigned fenc(float f){
    unsigned u = __float_as_uint(f);
    return (u & 0x80000000u) ? ~u : (u | 0x80000000u);
}
__device__ __forceinline__ float fdec(unsigned k){
    unsigned u = (k & 0x80000000u) ? (k & 0x7FFFFFFFu) : ~k;
    return __uint_as_float(u);
}

__global__ void k_sentinel(float* __restrict__ out, float v){ out[0] = v; }

// ---------------- zero / init helpers ----------------
__global__ void k_zero_f(float* __restrict__ p, int n){
    int i = blockIdx.x*blockDim.x + threadIdx.x;
    if(i < n) p[i] = 0.f;
}
__global__ void k_init_m(unsigned* __restrict__ p, int n){
    int i = blockIdx.x*blockDim.x + threadIdx.x;
    if(i < n) p[i] = fenc(-3.0e38f);
}

// ---------------- time embedding MLP (B=8 rows) ----------------
__global__ void k_tvec(const int* __restrict__ tg, const float* __restrict__ w1,
                       const float* __restrict__ b1, const float* __restrict__ w2,
                       const float* __restrict__ b2, float* __restrict__ tvec){
    int b = blockIdx.x, j = threadIdx.x;     // blockDim = 192
    __shared__ float emb[H], h1[H];
    float t = (float)tg[b];
    if(j < 96){
        float fr = __expf(-logf(10000.0f) * (float)j / 96.0f);
        float ang = t * fr;
        emb[j]      = sinf(ang);
        emb[j + 96] = cosf(ang);
    }
    __syncthreads();
    float acc = b1[j];
    for(int k = 0; k < H; k++) acc += emb[k] * w1[k*H + j];
    h1[j] = acc / (1.f + __expf(-acc));      // silu
    __syncthreads();
    float acc2 = b2[j];
    for(int k = 0; k < H; k++) acc2 += h1[k] * w2[k*H + j];
    tvec[b*H + j] = acc2;
}

// ---------------- x0 = node_emb[type] + t_vec[batch] + mask_emb[mask] ----------------
__global__ void k_init_x(const float* __restrict__ nemb, const float* __restrict__ memb,
                         const float* __restrict__ tvec, const int* __restrict__ ntype,
                         const int* __restrict__ emask, const int* __restrict__ nbatch,
                         float* __restrict__ x){
    int idx = blockIdx.x*blockDim.x + threadIdx.x;
    if(idx >= NN*H) return;
    int n = idx / H, c = idx % H;
    x[idx] = nemb[(size_t)ntype[n]*H + c] + tvec[nbatch[n]*H + c]
           + memb[(size_t)emask[n]*H + c];
}

// ---------------- e-tables: etab[l][b*8+et] = (edge_emb[et]+tvec[b]) @ we[l] ----------------
__global__ void k_etab(const float* __restrict__ eemb, const float* __restrict__ tvec,
                       const float* __restrict__ we, float* __restrict__ etab){
    int blk = blockIdx.x;                 // l*64 + idx
    int l = blk >> 6, idx = blk & 63, b = idx >> 3, et = idx & 7;
    int c = threadIdx.x;                  // 192
    __shared__ float a[H];
    a[c] = eemb[et*H + c] + tvec[b*H + c];
    __syncthreads();
    float acc = 0.f;
    const float* w = we + (size_t)l*HH;
    for(int k = 0; k < H; k++) acc += a[k] * w[k*H + c];
    etab[(size_t)blk*H + c] = acc;
}

// ---------------- c-table for final edge MLP (edge_attr & t_edge parts + b1) ----------------
__global__ void k_ctab(const float* __restrict__ eemb, const float* __restrict__ tvec,
                       const float* __restrict__ w1, const float* __restrict__ b1,
                       float* __restrict__ ctab){
    int idx = blockIdx.x, b = idx >> 3, et = idx & 7;
    int c = threadIdx.x;
    __shared__ float a[H];
    a[c] = eemb[et*H + c] + tvec[b*H + c];
    __syncthreads();
    float acc = b1[c];
    for(int k = 0; k < H; k++){
        acc += a[k]          * w1[(size_t)(2*H + k)*H + c];
        acc += tvec[b*H + k] * w1[(size_t)(3*H + k)*H + c];
    }
    ctab[(size_t)idx*H + c] = acc;
}

// ---------------- VALU GEMM, 4 weight mats, 8 nodes per block of 192 threads ----------------
__global__ __launch_bounds__(192) void k_vgemm4(
    const float* __restrict__ x,
    const float* __restrict__ wq, const float* __restrict__ wk,
    const float* __restrict__ wv, const float* __restrict__ wsk,
    const float* __restrict__ bq, const float* __restrict__ bk,
    const float* __restrict__ bv, const float* __restrict__ bsk,
    float* __restrict__ Q, float* __restrict__ K,
    float* __restrict__ V, float* __restrict__ XR)
{
    __shared__ float xs[8][H];
    int c = threadIdx.x;
    int n0 = blockIdx.x*8;
    #pragma unroll
    for(int i = 0; i < 8; i++) xs[i][c] = x[(size_t)(n0+i)*H + c];
    __syncthreads();
    float aq[8], ak[8], av[8], ax[8];
    #pragma unroll
    for(int i = 0; i < 8; i++){ aq[i]=0.f; ak[i]=0.f; av[i]=0.f; ax[i]=0.f; }
    for(int k = 0; k < H; k++){
        float w0 = wq[k*H + c], w1 = wk[k*H + c], w2 = wv[k*H + c], w3 = wsk[k*H + c];
        #pragma unroll
        for(int i = 0; i < 8; i++){
            float xv = xs[i][k];
            aq[i] += xv*w0; ak[i] += xv*w1; av[i] += xv*w2; ax[i] += xv*w3;
        }
    }
    float b0 = bq[c], b1 = bk[c], b2 = bv[c], b3 = bsk[c];
    #pragma unroll
    for(int i = 0; i < 8; i++){
        size_t o = (size_t)(n0+i)*H + c;
        Q[o] = aq[i] + b0; K[o] = ak[i] + b1; V[o] = av[i] + b2; XR[o] = ax[i] + b3;
    }
}

// ---------------- VALU GEMM, 2 mats (edge_w1 rows [0:H) and [H:2H)), no bias ----------------
__global__ __launch_bounds__(192) void k_vgemm2(
    const float* __restrict__ x, const float* __restrict__ ew1,
    float* __restrict__ xs1, float* __restrict__ xd1)
{
    __shared__ float xs[8][H];
    int c = threadIdx.x;
    int n0 = blockIdx.x*8;
    #pragma unroll
    for(int i = 0; i < 8; i++) xs[i][c] = x[(size_t)(n0+i)*H + c];
    __syncthreads();
    float as[8], ad[8];
    #pragma unroll
    for(int i = 0; i < 8; i++){ as[i]=0.f; ad[i]=0.f; }
    for(int k = 0; k < H; k++){
        float w0 = ew1[k*H + c], w1 = ew1[(size_t)HH + k*H + c];
        #pragma unroll
        for(int i = 0; i < 8; i++){
            float xv = xs[i][k];
            as[i] += xv*w0; ad[i] += xv*w1;
        }
    }
    #pragma unroll
    for(int i = 0; i < 8; i++){
        size_t o = (size_t)(n0+i)*H + c;
        xs1[o] = as[i]; xd1[o] = ad[i];
    }
}

// ---------------- attention pass A: score[e,h] + segment_max via atomicMax ----------------
__global__ void k_score(const float* __restrict__ Q, const float* __restrict__ K,
                        const float* __restrict__ etab,
                        const int* __restrict__ esrc, const int* __restrict__ edst,
                        const int* __restrict__ etype, const int* __restrict__ nbatch,
                        float* __restrict__ sc, unsigned* __restrict__ mkey)
{
    int t = blockIdx.x*blockDim.x + threadIdx.x;
    if(t >= NE*NHEAD) return;
    int e = t >> 2, h = t & 3;
    int s = esrc[e], d = edst[e];
    int eix = nbatch[s]*VEt + etype[e];
    const float* qp = Q    + (size_t)d*H   + h*CC;
    const float* kp = K    + (size_t)s*H   + h*CC;
    const float* ep = etab + (size_t)eix*H + h*CC;
    float acc = 0.f;
    for(int c = 0; c < CC; c++) acc += qp[c] * (kp[c] + ep[c]);
    float scv = acc * 0.14433756729740646f;   // 1/sqrt(48)
    sc[t] = scv;
    atomicMax(&mkey[d*NHEAD + h], fenc(scv));
}

// ---------------- attention pass B: ex = exp(sc-m), denom += ex ----------------
__global__ void k_expdenom(const int* __restrict__ edst, const unsigned* __restrict__ mkey,
                           float* __restrict__ sc, float* __restrict__ denom)
{
    int t = blockIdx.x*blockDim.x + threadIdx.x;
    if(t >= NE*NHEAD) return;
    int e = t >> 2, h = t & 3;
    int d = edst[e];
    float m = fdec(mkey[d*NHEAD + h]);
    float ex = __expf(sc[t] - m);
    sc[t] = ex;
    atomicAdd(&denom[d*NHEAD + h], ex);
}

// ---------------- attention pass C: out[d,h,c] += ex/denom * (v[s]+e) ----------------
__global__ void k_aggr(const float* __restrict__ V, const float* __restrict__ etab,
                       const int* __restrict__ esrc, const int* __restrict__ edst,
                       const int* __restrict__ etype, const int* __restrict__ nbatch,
                       const float* __restrict__ sc, const float* __restrict__ denom,
                       float* __restrict__ aout)
{
    int t = blockIdx.x*blockDim.x + threadIdx.x;
    if(t >= NE*NHEAD) return;
    int e = t >> 2, h = t & 3;
    int s = esrc[e], d = edst[e];
    int eix = nbatch[s]*VEt + etype[e];
    float w = sc[t] / denom[d*NHEAD + h];
    const float* vp = V    + (size_t)s*H   + h*CC;
    const float* ep = etab + (size_t)eix*H + h*CC;
    float* op = aout + (size_t)d*H + h*CC;
    for(int c = 0; c < CC; c++) atomicAdd(&op[c], w * (vp[c] + ep[c]));
}

// ---------------- epilogue: gate + blend + LayerNorm, one block(192) per node ----------------
__global__ __launch_bounds__(192) void k_epilogue(
    const float* __restrict__ aout, const float* __restrict__ XR,
    const float* __restrict__ wb, const float* __restrict__ lng,
    const float* __restrict__ lnb, float* __restrict__ x)
{
    __shared__ float red[192];
    __shared__ float sval;
    int n = blockIdx.x, c = threadIdx.x;
    size_t o = (size_t)n*H + c;
    float ov = aout[o], xr = XR[o];
    red[c] = ov*wb[c] + xr*wb[H + c] + (ov - xr)*wb[2*H + c];
    __syncthreads();
    if(c < 64) red[c] += red[c + 64] + red[c + 128];
    __syncthreads();
    for(int st = 32; st >= 1; st >>= 1){
        if(c < st) red[c] += red[c + st];
        __syncthreads();
    }
    if(c == 0) sval = 1.f / (1.f + __expf(-red[0]));
    __syncthreads();
    float beta = sval;
    float hcv = beta*xr + (1.f - beta)*ov;
    float y = x[o] + hcv;
    red[c] = y;
    __syncthreads();
    if(c < 64) red[c] += red[c + 64] + red[c + 128];
    __syncthreads();
    for(int st = 32; st >= 1; st >>= 1){
        if(c < st) red[c] += red[c + st];
        __syncthreads();
    }
    if(c == 0) sval = red[0] * (1.f/H);
    __syncthreads();
    float mean = sval;
    float dvv = y - mean;
    red[c] = dvv*dvv;
    __syncthreads();
    if(c < 64) red[c] += red[c + 64] + red[c + 128];
    __syncthreads();
    for(int st = 32; st >= 1; st >>= 1){
        if(c < st) red[c] += red[c + st];
        __syncthreads();
    }
    if(c == 0) sval = rsqrtf(red[0]*(1.f/H) + 1e-5f);
    __syncthreads();
    x[o] = dvv*sval*lng[c] + lnb[c];
}

// ---------------- node logits: x @ node_out_w + b, 32 lanes per node, fp32 out ----------------
__global__ void k_nodeout(const float* __restrict__ x, const float* __restrict__ w,
                          const float* __restrict__ b, float* __restrict__ out){
    int j = threadIdx.x & 31;
    int n = blockIdx.x*8 + (threadIdx.x >> 5);
    float acc = b[j];
    const float* xr = x + (size_t)n*H;
    for(int k = 0; k < H; k++) acc += xr[k] * w[k*32 + j];
    out[(size_t)n*32 + j] = acc;
}

// ---------------- edge logits: silu(xs1[s]+xd1[d]+ctab) @ edge_w2 + b2, fp32 out ----------------
__global__ __launch_bounds__(192) void k_edgemlp(
    const int* __restrict__ esrc, const int* __restrict__ edst, const int* __restrict__ etype,
    const int* __restrict__ nb,
    const float* __restrict__ xs1, const float* __restrict__ xd1, const float* __restrict__ ctab,
    const float* __restrict__ w2, const float* __restrict__ b2p, float* __restrict__ out)
{
    __shared__ float hsh[H];
    __shared__ float red[192];
    int e = blockIdx.x, c = threadIdx.x;
    int s = esrc[e], d = edst[e];
    int ct = nb[s]*VEt + etype[e];
    float v = xs1[(size_t)s*H + c] + xd1[(size_t)d*H + c] + ctab[(size_t)ct*H + c];
    hsh[c] = v / (1.f + __expf(-v));
    __syncthreads();
    for(int j = 0; j < 8; j++){
        red[c] = hsh[c] * w2[c*8 + j];
        __syncthreads();
        if(c < 64) red[c] += red[c + 64] + red[c + 128];
        __syncthreads();
        for(int st = 32; st >= 1; st >>= 1){
            if(c < st) red[c] += red[c + st];
            __syncthreads();
        }
        if(c == 0) out[(size_t)e*8 + j] = red[0] + b2p[j];
        __syncthreads();
    }
}

extern "C" void kernel_launch(void* const* d_in, const int* in_sizes, int n_in,
                              void* d_out, int out_size, void* d_ws, size_t ws_size,
                              hipStream_t stream)
{
    {
        int bad = -1;
        if(n_in != 31) bad = 100;
        else {
            const int chk_idx[9] = {0, 7, 16, 21, 23, 26, 27, 29, 30};
            const int chk_sz [9] = {32*H, NL*HH, NL*3*H, 4*HH, H*8, NE, 2*NE, NN, NBATCH};
            for(int i = 0; i < 9; i++) if(in_sizes[chk_idx[i]] != chk_sz[i]){ bad = chk_idx[i]; break; }
        }
        if(bad >= 0){
            k_sentinel<<<1, 1, 0, stream>>>((float*)d_out, 20000.f + 256.f*bad);
            return;
        }
        if(out_size != NN*32 + NE*8){
            k_sentinel<<<1, 1, 0, stream>>>((float*)d_out, 30000.f);
            return;
        }
    }

    const float* node_emb = (const float*)d_in[0];
    const float* edge_emb = (const float*)d_in[1];
    const float* time_w1  = (const float*)d_in[2];
    const float* time_b1  = (const float*)d_in[3];
    const float* time_w2  = (const float*)d_in[4];
    const float* time_b2  = (const float*)d_in[5];
    const float* mask_emb = (const float*)d_in[6];
    const float* wq       = (const float*)d_in[7];
    const float* bq       = (const float*)d_in[8];
    const float* wk       = (const float*)d_in[9];
    const float* bk       = (const float*)d_in[10];
    const float* wv       = (const float*)d_in[11];
    const float* bv       = (const float*)d_in[12];
    const float* we       = (const float*)d_in[13];
    const float* wskip    = (const float*)d_in[14];
    const float* bskip    = (const float*)d_in[15];
    const float* wbeta    = (const float*)d_in[16];
    const float* ln_g     = (const float*)d_in[17];
    const float* ln_b     = (const float*)d_in[18];
    const float* now      = (const float*)d_in[19];
    const float* nob      = (const float*)d_in[20];
    const float* ew1      = (const float*)d_in[21];
    const float* eb1      = (const float*)d_in[22];
    const float* ew2      = (const float*)d_in[23];
    const float* eb2      = (const float*)d_in[24];
    const int* node_type  = (const int*)d_in[25];
    const int* edge_type  = (const int*)d_in[26];
    const int* edge_index = (const int*)d_in[27];
    const int* edit_mask  = (const int*)d_in[28];
    const int* node_batch = (const int*)d_in[29];
    const int* t_graph    = (const int*)d_in[30];
    const int* esrc = edge_index;
    const int* edst = edge_index + NE;

    char* wsb = (char*)d_ws;
    size_t off = 0;
    auto take = [&](size_t bytes) -> char* {
        char* r = wsb + off;
        off += (bytes + 255) & ~(size_t)255;
        return r;
    };
    float*    tvec  = (float*)   take((size_t)NBATCH*H*4);
    float*    x     = (float*)   take((size_t)NN*H*4);
    float*    Q     = (float*)   take((size_t)NN*H*4);
    float*    Kb    = (float*)   take((size_t)NN*H*4);
    float*    Vb    = (float*)   take((size_t)NN*H*4);
    float*    XR    = (float*)   take((size_t)NN*H*4);
    float*    aout  = (float*)   take((size_t)NN*H*4);
    float*    etab  = (float*)   take((size_t)NL*64*H*4);
    float*    ctab  = (float*)   take((size_t)64*H*4);
    unsigned* mkey  = (unsigned*)take((size_t)NN*NHEAD*4);
    float*    denom = (float*)   take((size_t)NN*NHEAD*4);
    float*    sc    = (float*)   take((size_t)NE*NHEAD*4);
    float* xs1 = Q;   // reuse after layers
    float* xd1 = Kb;

    if(ws_size < off){
        k_sentinel<<<1, 1, 0, stream>>>((float*)d_out, 10000.f + (float)(ws_size >> 20));
        return;
    }

    k_tvec<<<NBATCH, H, 0, stream>>>(t_graph, time_w1, time_b1, time_w2, time_b2, tvec);
    k_init_x<<<(NN*H + 255)/256, 256, 0, stream>>>(node_emb, mask_emb, tvec, node_type,
                                                   edit_mask, node_batch, x);
    k_etab<<<NL*64, H, 0, stream>>>(edge_emb, tvec, we, etab);
    k_ctab<<<64, H, 0, stream>>>(edge_emb, tvec, ew1, eb1, ctab);

    const int EH = NE*NHEAD;
    for(int l = 0; l < NL; l++){
        k_vgemm4<<<NN/8, H, 0, stream>>>(x,
            wq + (size_t)l*HH, wk + (size_t)l*HH, wv + (size_t)l*HH, wskip + (size_t)l*HH,
            bq + (size_t)l*H,  bk + (size_t)l*H,  bv + (size_t)l*H,  bskip + (size_t)l*H,
            Q, Kb, Vb, XR);
        k_init_m<<<(NN*NHEAD + 255)/256, 256, 0, stream>>>(mkey, NN*NHEAD);
        k_zero_f<<<(NN*NHEAD + 255)/256, 256, 0, stream>>>(denom, NN*NHEAD);
        k_zero_f<<<(NN*H + 255)/256, 256, 0, stream>>>(aout, NN*H);
        k_score<<<(EH + 255)/256, 256, 0, stream>>>(Q, Kb, etab + (size_t)l*64*H,
                                                    esrc, edst, edge_type, node_batch, sc, mkey);
        k_expdenom<<<(EH + 255)/256, 256, 0, stream>>>(edst, mkey, sc, denom);
        k_aggr<<<(EH + 255)/256, 256, 0, stream>>>(Vb, etab + (size_t)l*64*H,
                                                   esrc, edst, edge_type, node_batch, sc, denom, aout);
        k_epilogue<<<NN, H, 0, stream>>>(aout, XR, wbeta + (size_t)l*3*H,
                                         ln_g + (size_t)l*H, ln_b + (size_t)l*H, x);
    }
    k_vgemm2<<<NN/8, H, 0, stream>>>(x, ew1, xs1, xd1);
    k_nodeout<<<NN/8, 256, 0, stream>>>(x, now, nob, (float*)d_out);
    k_edgemlp<<<NE, H, 0, stream>>>(esrc, edst, edge_type, node_batch, xs1, xd1, ctab,
                                    ew2, eb2, (float*)d_out + (size_t)NN*32);
}

// Round 8
// 994.705 us; speedup vs baseline: 12.4174x; 12.4174x over previous
//
#include <hip/hip_runtime.h>
#include <hip/hip_bf16.h>
#include <math.h>

#define NN 16000
#define NE 256000
#define H 192
#define NHEAD 4
#define CC 48
#define NL 4
#define NBATCH 8
#define VEt 8
#define HH (H*H)

__global__ void k_sentinel(float* __restrict__ out, float v){ out[0] = v; }

// ---------------- time embedding MLP (B=8 rows) ----------------
__global__ void k_tvec(const int* __restrict__ tg, const float* __restrict__ w1,
                       const float* __restrict__ b1, const float* __restrict__ w2,
                       const float* __restrict__ b2, float* __restrict__ tvec){
    int b = blockIdx.x, j = threadIdx.x;     // blockDim = 192
    __shared__ float emb[H], h1[H];
    float t = (float)tg[b];
    if(j < 96){
        float fr = __expf(-logf(10000.0f) * (float)j / 96.0f);
        float ang = t * fr;
        emb[j]      = sinf(ang);
        emb[j + 96] = cosf(ang);
    }
    __syncthreads();
    float acc = b1[j];
    for(int k = 0; k < H; k++) acc += emb[k] * w1[k*H + j];
    h1[j] = acc / (1.f + __expf(-acc));      // silu
    __syncthreads();
    float acc2 = b2[j];
    for(int k = 0; k < H; k++) acc2 += h1[k] * w2[k*H + j];
    tvec[b*H + j] = acc2;
}

// ---------------- x0 = node_emb[type] + t_vec[batch] + mask_emb[mask] ----------------
__global__ void k_init_x(const float* __restrict__ nemb, const float* __restrict__ memb,
                         const float* __restrict__ tvec, const int* __restrict__ ntype,
                         const int* __restrict__ emask, const int* __restrict__ nbatch,
                         float* __restrict__ x){
    int idx = blockIdx.x*blockDim.x + threadIdx.x;
    if(idx >= NN*H) return;
    int n = idx / H, c = idx % H;
    x[idx] = nemb[(size_t)ntype[n]*H + c] + tvec[nbatch[n]*H + c]
           + memb[(size_t)emask[n]*H + c];
}

// ---------------- counting sort of edges by dst ----------------
__global__ void k_zero_i(int* __restrict__ p, int n){
    int i = blockIdx.x*blockDim.x + threadIdx.x;
    if(i < n) p[i] = 0;
}
__global__ void k_count(const int* __restrict__ edst, int* __restrict__ cnt){
    int e = blockIdx.x*blockDim.x + threadIdx.x;
    if(e < NE) atomicAdd(&cnt[edst[e]], 1);
}
__global__ __launch_bounds__(1024) void k_scan(const int* __restrict__ cnt,
                                               int* __restrict__ ofs, int* __restrict__ cur){
    __shared__ int buf[1024];
    __shared__ int carry;
    int tid = threadIdx.x;
    if(tid == 0) carry = 0;
    __syncthreads();
    for(int base = 0; base < NN; base += 1024){
        int v = (base + tid < NN) ? cnt[base + tid] : 0;
        buf[tid] = v; __syncthreads();
        for(int o = 1; o < 1024; o <<= 1){
            int t = (tid >= o) ? buf[tid - o] : 0;
            __syncthreads();
            buf[tid] += t;
            __syncthreads();
        }
        int excl = buf[tid] - v;
        int c = carry;
        if(base + tid < NN){ ofs[base + tid] = c + excl; cur[base + tid] = c + excl; }
        __syncthreads();
        if(tid == 0) carry = c + buf[1023];
        __syncthreads();
    }
    if(tid == 0) ofs[NN] = carry;
}
__global__ void k_scatter(const int* __restrict__ esrc, const int* __restrict__ edst,
                          const int* __restrict__ etype, const int* __restrict__ nbatch,
                          int* __restrict__ cur, int* __restrict__ ssrc, int* __restrict__ seix){
    int e = blockIdx.x*blockDim.x + threadIdx.x;
    if(e >= NE) return;
    int s = esrc[e], d = edst[e];
    int pos = atomicAdd(&cur[d], 1);
    ssrc[pos] = s;
    seix[pos] = nbatch[s]*VEt + etype[e];
}

// ---------------- e-tables: etab[l][b*8+et] = (edge_emb[et]+tvec[b]) @ we[l] ----------------
__global__ void k_etab(const float* __restrict__ eemb, const float* __restrict__ tvec,
                       const float* __restrict__ we, float* __restrict__ etab){
    int blk = blockIdx.x;                 // l*64 + idx
    int l = blk >> 6, idx = blk & 63, b = idx >> 3, et = idx & 7;
    int c = threadIdx.x;                  // 192
    __shared__ float a[H];
    a[c] = eemb[et*H + c] + tvec[b*H + c];
    __syncthreads();
    float acc = 0.f;
    const float* w = we + (size_t)l*HH;
    for(int k = 0; k < H; k++) acc += a[k] * w[k*H + c];
    etab[(size_t)blk*H + c] = acc;
}

// ---------------- c-table for final edge MLP (edge_attr & t_edge parts + b1) ----------------
__global__ void k_ctab(const float* __restrict__ eemb, const float* __restrict__ tvec,
                       const float* __restrict__ w1, const float* __restrict__ b1,
                       float* __restrict__ ctab){
    int idx = blockIdx.x, b = idx >> 3, et = idx & 7;
    int c = threadIdx.x;
    __shared__ float a[H];
    a[c] = eemb[et*H + c] + tvec[b*H + c];
    __syncthreads();
    float acc = b1[c];
    for(int k = 0; k < H; k++){
        acc += a[k]          * w1[(size_t)(2*H + k)*H + c];
        acc += tvec[b*H + k] * w1[(size_t)(3*H + k)*H + c];
    }
    ctab[(size_t)idx*H + c] = acc;
}

// ---------------- VALU GEMM, 4 weight mats, 8 nodes per block of 192 threads ----------------
__global__ __launch_bounds__(192) void k_vgemm4(
    const float* __restrict__ x,
    const float* __restrict__ wq, const float* __restrict__ wk,
    const float* __restrict__ wv, const float* __restrict__ wsk,
    const float* __restrict__ bq, const float* __restrict__ bk,
    const float* __restrict__ bv, const float* __restrict__ bsk,
    float* __restrict__ Q, float* __restrict__ K,
    float* __restrict__ V, float* __restrict__ XR)
{
    __shared__ float xs[8][H];
    int c = threadIdx.x;
    int n0 = blockIdx.x*8;
    #pragma unroll
    for(int i = 0; i < 8; i++) xs[i][c] = x[(size_t)(n0+i)*H + c];
    __syncthreads();
    float aq[8], ak[8], av[8], ax[8];
    #pragma unroll
    for(int i = 0; i < 8; i++){ aq[i]=0.f; ak[i]=0.f; av[i]=0.f; ax[i]=0.f; }
    for(int k = 0; k < H; k++){
        float w0 = wq[k*H + c], w1 = wk[k*H + c], w2 = wv[k*H + c], w3 = wsk[k*H + c];
        #pragma unroll
        for(int i = 0; i < 8; i++){
            float xv = xs[i][k];
            aq[i] += xv*w0; ak[i] += xv*w1; av[i] += xv*w2; ax[i] += xv*w3;
        }
    }
    float b0 = bq[c], b1 = bk[c], b2 = bv[c], b3 = bsk[c];
    #pragma unroll
    for(int i = 0; i < 8; i++){
        size_t o = (size_t)(n0+i)*H + c;
        Q[o] = aq[i] + b0; K[o] = ak[i] + b1; V[o] = av[i] + b2; XR[o] = ax[i] + b3;
    }
}

// ---------------- VALU GEMM, 2 mats (edge_w1 rows [0:H) and [H:2H)), no bias ----------------
__global__ __launch_bounds__(192) void k_vgemm2(
    const float* __restrict__ x, const float* __restrict__ ew1,
    float* __restrict__ xs1, float* __restrict__ xd1)
{
    __shared__ float xs[8][H];
    int c = threadIdx.x;
    int n0 = blockIdx.x*8;
    #pragma unroll
    for(int i = 0; i < 8; i++) xs[i][c] = x[(size_t)(n0+i)*H + c];
    __syncthreads();
    float as[8], ad[8];
    #pragma unroll
    for(int i = 0; i < 8; i++){ as[i]=0.f; ad[i]=0.f; }
    for(int k = 0; k < H; k++){
        float w0 = ew1[k*H + c], w1 = ew1[(size_t)HH + k*H + c];
        #pragma unroll
        for(int i = 0; i < 8; i++){
            float xv = xs[i][k];
            as[i] += xv*w0; ad[i] += xv*w1;
        }
    }
    #pragma unroll
    for(int i = 0; i < 8; i++){
        size_t o = (size_t)(n0+i)*H + c;
        xs1[o] = as[i]; xd1[o] = ad[i];
    }
}

// ---------------- fused attention + gate + LayerNorm, one wave per node ----------------
__global__ __launch_bounds__(256) void k_attn(
    const float* __restrict__ Q, const float* __restrict__ K,
    const float* __restrict__ V, const float* __restrict__ XR,
    const float* __restrict__ etab, const int* __restrict__ ofs,
    const int* __restrict__ ssrc, const int* __restrict__ seix,
    const float* __restrict__ wb, const float* __restrict__ lng, const float* __restrict__ lnb,
    float* __restrict__ x)
{
    int n = blockIdx.x*4 + (threadIdx.x >> 6);
    int lane = threadIdx.x & 63;
    int ch = lane*3;                       // head = lane>>4 (48 ch per 16 lanes)
    size_t base = (size_t)n*H + ch;
    const float scale = 0.14433756729740646f;   // 1/sqrt(48)
    float q0 = Q[base], q1 = Q[base+1], q2 = Q[base+2];
    int p0 = ofs[n], p1 = ofs[n+1];
    float m = -3.0e38f, l = 0.f, a0 = 0.f, a1 = 0.f, a2 = 0.f;
    for(int p = p0; p < p1; p++){
        int s  = ssrc[p];
        int ei = seix[p];
        const float* kp = K    + (size_t)s*H  + ch;
        const float* ep = etab + (size_t)ei*H + ch;
        float e0 = ep[0], e1 = ep[1], e2 = ep[2];
        float t = q0*(kp[0]+e0) + q1*(kp[1]+e1) + q2*(kp[2]+e2);
        t += __shfl_xor(t,1); t += __shfl_xor(t,2); t += __shfl_xor(t,4); t += __shfl_xor(t,8);
        float sc = t*scale;
        float mn = fmaxf(m, sc);
        float corr = __expf(m - mn);
        float pw   = __expf(sc - mn);
        const float* vp = V + (size_t)s*H + ch;
        l  = l*corr + pw;
        a0 = a0*corr + pw*(vp[0]+e0);
        a1 = a1*corr + pw*(vp[1]+e1);
        a2 = a2*corr + pw*(vp[2]+e2);
        m = mn;
    }
    float inv = (p1 > p0) ? 1.f/l : 0.f;
    float o0 = a0*inv, o1 = a1*inv, o2 = a2*inv;
    float xr0 = XR[base], xr1 = XR[base+1], xr2 = XR[base+2];
    float sd = o0*wb[ch]  + o1*wb[ch+1]  + o2*wb[ch+2]
             + xr0*wb[H+ch] + xr1*wb[H+ch+1] + xr2*wb[H+ch+2]
             + (o0-xr0)*wb[2*H+ch] + (o1-xr1)*wb[2*H+ch+1] + (o2-xr2)*wb[2*H+ch+2];
    sd += __shfl_xor(sd,1); sd += __shfl_xor(sd,2); sd += __shfl_xor(sd,4);
    sd += __shfl_xor(sd,8); sd += __shfl_xor(sd,16); sd += __shfl_xor(sd,32);
    float beta = 1.f/(1.f + __expf(-sd));
    float h0 = beta*xr0 + (1.f-beta)*o0;
    float h1 = beta*xr1 + (1.f-beta)*o1;
    float h2 = beta*xr2 + (1.f-beta)*o2;
    float y0 = x[base] + h0, y1 = x[base+1] + h1, y2 = x[base+2] + h2;
    float s3 = y0 + y1 + y2;
    s3 += __shfl_xor(s3,1); s3 += __shfl_xor(s3,2); s3 += __shfl_xor(s3,4);
    s3 += __shfl_xor(s3,8); s3 += __shfl_xor(s3,16); s3 += __shfl_xor(s3,32);
    float mean = s3 * (1.f/H);
    float d0 = y0-mean, d1 = y1-mean, d2 = y2-mean;
    float v3 = d0*d0 + d1*d1 + d2*d2;
    v3 += __shfl_xor(v3,1); v3 += __shfl_xor(v3,2); v3 += __shfl_xor(v3,4);
    v3 += __shfl_xor(v3,8); v3 += __shfl_xor(v3,16); v3 += __shfl_xor(v3,32);
    float rs = rsqrtf(v3*(1.f/H) + 1e-5f);
    x[base]   = d0*rs*lng[ch]   + lnb[ch];
    x[base+1] = d1*rs*lng[ch+1] + lnb[ch+1];
    x[base+2] = d2*rs*lng[ch+2] + lnb[ch+2];
}

// ---------------- node logits: x @ node_out_w + b, 32 lanes per node, fp32 out ----------------
__global__ void k_nodeout(const float* __restrict__ x, const float* __restrict__ w,
                          const float* __restrict__ b, float* __restrict__ out){
    int j = threadIdx.x & 31;
    int n = blockIdx.x*8 + (threadIdx.x >> 5);
    float acc = b[j];
    const float* xr = x + (size_t)n*H;
    for(int k = 0; k < H; k++) acc += xr[k] * w[k*32 + j];
    out[(size_t)n*32 + j] = acc;
}

// ---------------- edge logits: silu(xs1[s]+xd1[d]+ctab) @ edge_w2 + b2, one wave/edge ----------------
__global__ __launch_bounds__(256) void k_edgemlp(
    const int* __restrict__ esrc, const int* __restrict__ edst, const int* __restrict__ etype,
    const int* __restrict__ nb,
    const float* __restrict__ xs1, const float* __restrict__ xd1, const float* __restrict__ ctab,
    const float* __restrict__ w2, const float* __restrict__ b2p, float* __restrict__ out)
{
    int e = blockIdx.x*4 + (threadIdx.x >> 6);
    int lane = threadIdx.x & 63;
    int s = esrc[e], d = edst[e];
    int ct = nb[s]*VEt + etype[e];
    int ch = lane*3;
    const float* ap = xs1 + (size_t)s*H + ch;
    const float* bp = xd1 + (size_t)d*H + ch;
    const float* cp = ctab + (size_t)ct*H + ch;
    float h0, h1, h2;
    { float v = ap[0]+bp[0]+cp[0]; h0 = v/(1.f+__expf(-v)); }
    { float v = ap[1]+bp[1]+cp[1]; h1 = v/(1.f+__expf(-v)); }
    { float v = ap[2]+bp[2]+cp[2]; h2 = v/(1.f+__expf(-v)); }
    float pj[8];
    #pragma unroll
    for(int j = 0; j < 8; j++)
        pj[j] = h0*w2[ch*8+j] + h1*w2[(ch+1)*8+j] + h2*w2[(ch+2)*8+j];
    #pragma unroll
    for(int j = 0; j < 8; j++){
        pj[j] += __shfl_xor(pj[j],1);  pj[j] += __shfl_xor(pj[j],2);
        pj[j] += __shfl_xor(pj[j],4);  pj[j] += __shfl_xor(pj[j],8);
        pj[j] += __shfl_xor(pj[j],16); pj[j] += __shfl_xor(pj[j],32);
    }
    if(lane < 8){
        out[(size_t)e*8 + lane] = pj[lane] + b2p[lane];
    }
}

extern "C" void kernel_launch(void* const* d_in, const int* in_sizes, int n_in,
                              void* d_out, int out_size, void* d_ws, size_t ws_size,
                              hipStream_t stream)
{
    {
        int bad = -1;
        if(n_in != 31) bad = 100;
        else {
            const int chk_idx[9] = {0, 7, 16, 21, 23, 26, 27, 29, 30};
            const int chk_sz [9] = {32*H, NL*HH, NL*3*H, 4*HH, H*8, NE, 2*NE, NN, NBATCH};
            for(int i = 0; i < 9; i++) if(in_sizes[chk_idx[i]] != chk_sz[i]){ bad = chk_idx[i]; break; }
        }
        if(bad >= 0){
            k_sentinel<<<1, 1, 0, stream>>>((float*)d_out, 20000.f + 256.f*bad);
            return;
        }
        if(out_size != NN*32 + NE*8){
            k_sentinel<<<1, 1, 0, stream>>>((float*)d_out, 30000.f);
            return;
        }
    }

    const float* node_emb = (const float*)d_in[0];
    const float* edge_emb = (const float*)d_in[1];
    const float* time_w1  = (const float*)d_in[2];
    const float* time_b1  = (const float*)d_in[3];
    const float* time_w2  = (const float*)d_in[4];
    const float* time_b2  = (const float*)d_in[5];
    const float* mask_emb = (const float*)d_in[6];
    const float* wq       = (const float*)d_in[7];
    const float* bq       = (const float*)d_in[8];
    const float* wk       = (const float*)d_in[9];
    const float* bk       = (const float*)d_in[10];
    const float* wv       = (const float*)d_in[11];
    const float* bv       = (const float*)d_in[12];
    const float* we       = (const float*)d_in[13];
    const float* wskip    = (const float*)d_in[14];
    const float* bskip    = (const float*)d_in[15];
    const float* wbeta    = (const float*)d_in[16];
    const float* ln_g     = (const float*)d_in[17];
    const float* ln_b     = (const float*)d_in[18];
    const float* now      = (const float*)d_in[19];
    const float* nob      = (const float*)d_in[20];
    const float* ew1      = (const float*)d_in[21];
    const float* eb1      = (const float*)d_in[22];
    const float* ew2      = (const float*)d_in[23];
    const float* eb2      = (const float*)d_in[24];
    const int* node_type  = (const int*)d_in[25];
    const int* edge_type  = (const int*)d_in[26];
    const int* edge_index = (const int*)d_in[27];
    const int* edit_mask  = (const int*)d_in[28];
    const int* node_batch = (const int*)d_in[29];
    const int* t_graph    = (const int*)d_in[30];
    const int* esrc = edge_index;
    const int* edst = edge_index + NE;

    char* wsb = (char*)d_ws;
    size_t off = 0;
    auto take = [&](size_t bytes) -> char* {
        char* r = wsb + off;
        off += (bytes + 255) & ~(size_t)255;
        return r;
    };
    float* tvec = (float*)take((size_t)NBATCH*H*4);
    float* x    = (float*)take((size_t)NN*H*4);
    float* Q    = (float*)take((size_t)NN*H*4);
    float* Kb   = (float*)take((size_t)NN*H*4);
    float* Vb   = (float*)take((size_t)NN*H*4);
    float* XR   = (float*)take((size_t)NN*H*4);
    float* etab = (float*)take((size_t)NL*64*H*4);
    float* ctab = (float*)take((size_t)64*H*4);
    int* cnt    = (int*)  take((size_t)(NN+1)*4);
    int* offa   = (int*)  take((size_t)(NN+1)*4);
    int* cur    = (int*)  take((size_t)(NN+1)*4);
    int* ssrc   = (int*)  take((size_t)NE*4);
    int* seix   = (int*)  take((size_t)NE*4);
    float* xs1 = Q;   // reuse after layers
    float* xd1 = Kb;

    if(ws_size < off){
        k_sentinel<<<1, 1, 0, stream>>>((float*)d_out, 10000.f + (float)(ws_size >> 20));
        return;
    }

    k_tvec<<<NBATCH, H, 0, stream>>>(t_graph, time_w1, time_b1, time_w2, time_b2, tvec);
    k_init_x<<<(NN*H + 255)/256, 256, 0, stream>>>(node_emb, mask_emb, tvec, node_type,
                                                   edit_mask, node_batch, x);
    k_zero_i<<<(NN + 255)/256, 256, 0, stream>>>(cnt, NN);
    k_count<<<NE/256, 256, 0, stream>>>(edst, cnt);
    k_scan<<<1, 1024, 0, stream>>>(cnt, offa, cur);
    k_scatter<<<NE/256, 256, 0, stream>>>(esrc, edst, edge_type, node_batch, cur, ssrc, seix);
    k_etab<<<NL*64, H, 0, stream>>>(edge_emb, tvec, we, etab);
    k_ctab<<<64, H, 0, stream>>>(edge_emb, tvec, ew1, eb1, ctab);

    for(int l = 0; l < NL; l++){
        k_vgemm4<<<NN/8, H, 0, stream>>>(x,
            wq + (size_t)l*HH, wk + (size_t)l*HH, wv + (size_t)l*HH, wskip + (size_t)l*HH,
            bq + (size_t)l*H,  bk + (size_t)l*H,  bv + (size_t)l*H,  bskip + (size_t)l*H,
            Q, Kb, Vb, XR);
        k_attn<<<NN/4, 256, 0, stream>>>(Q, Kb, Vb, XR, etab + (size_t)l*64*H, offa, ssrc, seix,
                                         wbeta + (size_t)l*3*H, ln_g + (size_t)l*H,
                                         ln_b + (size_t)l*H, x);
    }
    k_vgemm2<<<NN/8, H, 0, stream>>>(x, ew1, xs1, xd1);
    k_nodeout<<<NN/8, 256, 0, stream>>>(x, now, nob, (float*)d_out);
    k_edgemlp<<<NE/4, 256, 0, stream>>>(esrc, edst, edge_type, node_batch, xs1, xd1, ctab,
                                        ew2, eb2, (float*)d_out + (size_t)NN*32);
}

// Round 9
// 741.112 us; speedup vs baseline: 16.6664x; 1.3422x over previous
//
#include <hip/hip_runtime.h>
#include <hip/hip_bf16.h>
#include <math.h>

#define NN 16000
#define NPAD 16128
#define NE 256000
#define H 192
#define NL 4
#define NBATCH 8
#define VEt 8
#define HH (H*H)

typedef __hip_bfloat16 bf16;
typedef unsigned short u16;
typedef __attribute__((ext_vector_type(8))) short bfrag_t;
typedef __attribute__((ext_vector_type(4))) float facc_t;

__device__ __forceinline__ bf16 f2b(float v){ return __float2bfloat16(v); }
__device__ __forceinline__ float b2f(u16 v){ bf16 h; *(u16*)&h = v; return __bfloat162float(h); }

__global__ void k_sentinel(float* __restrict__ out, float v){ out[0] = v; }

// ---------------- transpose 18 H×H fp32 weight mats into bf16 [n][k] ----------------
__global__ void k_transpose(const float* __restrict__ wq, const float* __restrict__ wk,
                            const float* __restrict__ wv, const float* __restrict__ wsk,
                            const float* __restrict__ w1, u16* __restrict__ wt){
    int mat = blockIdx.x;
    const float* src;
    if(mat < 4)       src = wq  + (size_t)mat*HH;
    else if(mat < 8)  src = wk  + (size_t)(mat-4)*HH;
    else if(mat < 12) src = wv  + (size_t)(mat-8)*HH;
    else if(mat < 16) src = wsk + (size_t)(mat-12)*HH;
    else              src = w1  + (size_t)(mat-16)*HH;   // edge_w1 rows [0,H) and [H,2H)
    u16* dst = wt + (size_t)mat*HH;
    for(int i = threadIdx.x; i < HH; i += blockDim.x){
        int k = i / H, n = i % H;
        bf16 b = f2b(src[i]);
        dst[n*H + k] = *(u16*)&b;
    }
}

// ---------------- time embedding MLP ----------------
__global__ void k_tvec(const int* __restrict__ tg, const float* __restrict__ w1,
                       const float* __restrict__ b1, const float* __restrict__ w2,
                       const float* __restrict__ b2, float* __restrict__ tvec){
    int b = blockIdx.x, j = threadIdx.x;     // blockDim = 192
    __shared__ float emb[H], h1[H];
    float t = (float)tg[b];
    if(j < 96){
        float fr = __expf(-logf(10000.0f) * (float)j / 96.0f);
        float ang = t * fr;
        emb[j]      = sinf(ang);
        emb[j + 96] = cosf(ang);
    }
    __syncthreads();
    float acc = b1[j];
    for(int k = 0; k < H; k++) acc += emb[k] * w1[k*H + j];
    h1[j] = acc / (1.f + __expf(-acc));
    __syncthreads();
    float acc2 = b2[j];
    for(int k = 0; k < H; k++) acc2 += h1[k] * w2[k*H + j];
    tvec[b*H + j] = acc2;
}

// ---------------- x0 ----------------
__global__ void k_init_x(const float* __restrict__ nemb, const float* __restrict__ memb,
                         const float* __restrict__ tvec, const int* __restrict__ ntype,
                         const int* __restrict__ emask, const int* __restrict__ nbatch,
                         float* __restrict__ x, u16* __restrict__ xb){
    int idx = blockIdx.x*blockDim.x + threadIdx.x;
    if(idx >= NN*H) return;
    int n = idx / H, c = idx % H;
    float v = nemb[(size_t)ntype[n]*H + c] + tvec[nbatch[n]*H + c]
            + memb[(size_t)emask[n]*H + c];
    x[idx] = v;
    bf16 b = f2b(v); xb[idx] = *(u16*)&b;
}

// ---------------- counting sort of edges by dst ----------------
__global__ void k_zero_i(int* __restrict__ p, int n){
    int i = blockIdx.x*blockDim.x + threadIdx.x;
    if(i < n) p[i] = 0;
}
__global__ void k_count(const int* __restrict__ edst, int* __restrict__ cnt){
    int e = blockIdx.x*blockDim.x + threadIdx.x;
    if(e < NE) atomicAdd(&cnt[edst[e]], 1);
}
__global__ __launch_bounds__(1024) void k_scan(const int* __restrict__ cnt,
                                               int* __restrict__ ofs, int* __restrict__ cur){
    __shared__ int buf[1024];
    __shared__ int carry;
    int tid = threadIdx.x;
    if(tid == 0) carry = 0;
    __syncthreads();
    for(int base = 0; base < NN; base += 1024){
        int v = (base + tid < NN) ? cnt[base + tid] : 0;
        buf[tid] = v; __syncthreads();
        for(int o = 1; o < 1024; o <<= 1){
            int t = (tid >= o) ? buf[tid - o] : 0;
            __syncthreads();
            buf[tid] += t;
            __syncthreads();
        }
        int excl = buf[tid] - v;
        int c = carry;
        if(base + tid < NN){ ofs[base + tid] = c + excl; cur[base + tid] = c + excl; }
        __syncthreads();
        if(tid == 0) carry = c + buf[1023];
        __syncthreads();
    }
    if(tid == 0) ofs[NN] = carry;
}
__global__ void k_scatter(const int* __restrict__ esrc, const int* __restrict__ edst,
                          const int* __restrict__ etype, const int* __restrict__ nbatch,
                          int* __restrict__ cur, int* __restrict__ ssrc, int* __restrict__ seix){
    int e = blockIdx.x*blockDim.x + threadIdx.x;
    if(e >= NE) return;
    int s = esrc[e], d = edst[e];
    int pos = atomicAdd(&cur[d], 1);
    ssrc[pos] = s;
    seix[pos] = nbatch[s]*VEt + etype[e];
}

// ---------------- e-tables ----------------
__global__ void k_etab(const float* __restrict__ eemb, const float* __restrict__ tvec,
                       const float* __restrict__ we, float* __restrict__ etab){
    int blk = blockIdx.x;                 // l*64 + idx
    int l = blk >> 6, idx = blk & 63, b = idx >> 3, et = idx & 7;
    int c = threadIdx.x;
    __shared__ float a[H];
    a[c] = eemb[et*H + c] + tvec[b*H + c];
    __syncthreads();
    float acc = 0.f;
    const float* w = we + (size_t)l*HH;
    for(int k = 0; k < H; k++) acc += a[k] * w[k*H + c];
    etab[(size_t)blk*H + c] = acc;
}

// ---------------- c-table ----------------
__global__ void k_ctab(const float* __restrict__ eemb, const float* __restrict__ tvec,
                       const float* __restrict__ w1, const float* __restrict__ b1,
                       float* __restrict__ ctab){
    int idx = blockIdx.x, b = idx >> 3, et = idx & 7;
    int c = threadIdx.x;
    __shared__ float a[H];
    a[c] = eemb[et*H + c] + tvec[b*H + c];
    __syncthreads();
    float acc = b1[c];
    for(int k = 0; k < H; k++){
        acc += a[k]          * w1[(size_t)(2*H + k)*H + c];
        acc += tvec[b*H + k] * w1[(size_t)(3*H + k)*H + c];
    }
    ctab[(size_t)idx*H + c] = acc;
}

// ---------------- MFMA GEMM: out[oi] = A(bf16) @ Wt(oi) + bias(oi) ----------------
struct GemmP {
    const u16* wt[4];
    const float* bias[4];     // nullptr => 0
    void* out[4];
    int obf[4];               // 1 => bf16 output
};
__global__ __launch_bounds__(256) void k_gemm(const u16* __restrict__ A, GemmP P){
    int oi = blockIdx.y / 3, nt = blockIdx.y % 3;
    const u16* Wt = P.wt[oi];
    const float* bias = P.bias[oi];
    int wave = threadIdx.x >> 6, lane = threadIdx.x & 63;
    int quad = lane >> 4, l16 = lane & 15;
    int m0 = blockIdx.x*256 + wave*64;
    int n0 = nt*64;
    facc_t acc[4][4];
    #pragma unroll
    for(int i = 0; i < 4; i++)
        #pragma unroll
        for(int j = 0; j < 4; j++){ acc[i][j][0]=0.f; acc[i][j][1]=0.f; acc[i][j][2]=0.f; acc[i][j][3]=0.f; }
    #pragma unroll
    for(int kc = 0; kc < 6; kc++){
        int kb = kc*32 + quad*8;
        bfrag_t af[4], bg[4];
        #pragma unroll
        for(int i = 0; i < 4; i++) af[i] = *(const bfrag_t*)(A  + (size_t)(m0 + i*16 + l16)*H + kb);
        #pragma unroll
        for(int j = 0; j < 4; j++) bg[j] = *(const bfrag_t*)(Wt + (size_t)(n0 + j*16 + l16)*H + kb);
        #pragma unroll
        for(int i = 0; i < 4; i++)
            #pragma unroll
            for(int j = 0; j < 4; j++)
                acc[i][j] = __builtin_amdgcn_mfma_f32_16x16x32_bf16(af[i], bg[j], acc[i][j], 0, 0, 0);
    }
    float bv[4];
    #pragma unroll
    for(int j = 0; j < 4; j++) bv[j] = bias ? bias[n0 + j*16 + l16] : 0.f;
    if(P.obf[oi]){
        u16* out = (u16*)P.out[oi];
        #pragma unroll
        for(int i = 0; i < 4; i++){
            int rb = m0 + i*16 + quad*4;
            #pragma unroll
            for(int r = 0; r < 4; r++){
                int row = rb + r;
                if(row < NN){
                    #pragma unroll
                    for(int j = 0; j < 4; j++){
                        bf16 b = f2b(acc[i][j][r] + bv[j]);
                        out[(size_t)row*H + n0 + j*16 + l16] = *(u16*)&b;
                    }
                }
            }
        }
    } else {
        float* out = (float*)P.out[oi];
        #pragma unroll
        for(int i = 0; i < 4; i++){
            int rb = m0 + i*16 + quad*4;
            #pragma unroll
            for(int r = 0; r < 4; r++){
                int row = rb + r;
                if(row < NN){
                    #pragma unroll
                    for(int j = 0; j < 4; j++)
                        out[(size_t)row*H + n0 + j*16 + l16] = acc[i][j][r] + bv[j];
                }
            }
        }
    }
}

// ---------------- fused attention + gate + LayerNorm, one wave per node ----------------
__global__ __launch_bounds__(256) void k_attn(
    const float* __restrict__ Q, const u16* __restrict__ Kb,
    const u16* __restrict__ Vb, const float* __restrict__ XR,
    const float* __restrict__ etab, const int* __restrict__ ofs,
    const int* __restrict__ ssrc, const int* __restrict__ seix,
    const float* __restrict__ wb, const float* __restrict__ lng, const float* __restrict__ lnb,
    float* __restrict__ x, u16* __restrict__ xb)
{
    int n = blockIdx.x*4 + (threadIdx.x >> 6);
    int lane = threadIdx.x & 63;
    int ch = lane*3;                       // head = lane>>4 (48 ch per 16 lanes)
    size_t base = (size_t)n*H + ch;
    const float scale = 0.14433756729740646f;   // 1/sqrt(48)
    float q0 = Q[base], q1 = Q[base+1], q2 = Q[base+2];
    int p0 = ofs[n], p1 = ofs[n+1];
    float m = -3.0e38f, l = 0.f, a0 = 0.f, a1 = 0.f, a2 = 0.f;
    for(int p = p0; p < p1; p++){
        int s  = ssrc[p];
        int ei = seix[p];
        const u16*   kp = Kb   + (size_t)s*H  + ch;
        const float* ep = etab + (size_t)ei*H + ch;
        float e0 = ep[0], e1 = ep[1], e2 = ep[2];
        float t = q0*(b2f(kp[0])+e0) + q1*(b2f(kp[1])+e1) + q2*(b2f(kp[2])+e2);
        t += __shfl_xor(t,1); t += __shfl_xor(t,2); t += __shfl_xor(t,4); t += __shfl_xor(t,8);
        float sc = t*scale;
        float mn = fmaxf(m, sc);
        float corr = __expf(m - mn);
        float pw   = __expf(sc - mn);
        const u16* vp = Vb + (size_t)s*H + ch;
        l  = l*corr + pw;
        a0 = a0*corr + pw*(b2f(vp[0])+e0);
        a1 = a1*corr + pw*(b2f(vp[1])+e1);
        a2 = a2*corr + pw*(b2f(vp[2])+e2);
        m = mn;
    }
    float inv = (p1 > p0) ? 1.f/l : 0.f;
    float o0 = a0*inv, o1 = a1*inv, o2 = a2*inv;
    float xr0 = XR[base], xr1 = XR[base+1], xr2 = XR[base+2];
    float sd = o0*wb[ch]  + o1*wb[ch+1]  + o2*wb[ch+2]
             + xr0*wb[H+ch] + xr1*wb[H+ch+1] + xr2*wb[H+ch+2]
             + (o0-xr0)*wb[2*H+ch] + (o1-xr1)*wb[2*H+ch+1] + (o2-xr2)*wb[2*H+ch+2];
    sd += __shfl_xor(sd,1); sd += __shfl_xor(sd,2); sd += __shfl_xor(sd,4);
    sd += __shfl_xor(sd,8); sd += __shfl_xor(sd,16); sd += __shfl_xor(sd,32);
    float beta = 1.f/(1.f + __expf(-sd));
    float h0 = beta*xr0 + (1.f-beta)*o0;
    float h1 = beta*xr1 + (1.f-beta)*o1;
    float h2 = beta*xr2 + (1.f-beta)*o2;
    float y0 = x[base] + h0, y1 = x[base+1] + h1, y2 = x[base+2] + h2;
    float s3 = y0 + y1 + y2;
    s3 += __shfl_xor(s3,1); s3 += __shfl_xor(s3,2); s3 += __shfl_xor(s3,4);
    s3 += __shfl_xor(s3,8); s3 += __shfl_xor(s3,16); s3 += __shfl_xor(s3,32);
    float mean = s3 * (1.f/H);
    float d0 = y0-mean, d1 = y1-mean, d2 = y2-mean;
    float v3 = d0*d0 + d1*d1 + d2*d2;
    v3 += __shfl_xor(v3,1); v3 += __shfl_xor(v3,2); v3 += __shfl_xor(v3,4);
    v3 += __shfl_xor(v3,8); v3 += __shfl_xor(v3,16); v3 += __shfl_xor(v3,32);
    float rs = rsqrtf(v3*(1.f/H) + 1e-5f);
    float z0 = d0*rs*lng[ch]   + lnb[ch];
    float z1 = d1*rs*lng[ch+1] + lnb[ch+1];
    float z2 = d2*rs*lng[ch+2] + lnb[ch+2];
    x[base] = z0; x[base+1] = z1; x[base+2] = z2;
    bf16 t0 = f2b(z0), t1 = f2b(z1), t2 = f2b(z2);
    xb[base] = *(u16*)&t0; xb[base+1] = *(u16*)&t1; xb[base+2] = *(u16*)&t2;
}

// ---------------- node logits ----------------
__global__ void k_nodeout(const float* __restrict__ x, const float* __restrict__ w,
                          const float* __restrict__ b, float* __restrict__ out){
    int j = threadIdx.x & 31;
    int n = blockIdx.x*8 + (threadIdx.x >> 5);
    float acc = b[j];
    const float* xr = x + (size_t)n*H;
    for(int k = 0; k < H; k++) acc += xr[k] * w[k*32 + j];
    out[(size_t)n*32 + j] = acc;
}

// ---------------- edge logits: bf16 gathers + split-butterfly reduction ----------------
__global__ __launch_bounds__(256) void k_edgemlp(
    const int* __restrict__ esrc, const int* __restrict__ edst, const int* __restrict__ etype,
    const int* __restrict__ nb,
    const u16* __restrict__ xs1, const u16* __restrict__ xd1, const float* __restrict__ ctab,
    const float* __restrict__ w2, const float* __restrict__ b2p, float* __restrict__ out)
{
    int e = blockIdx.x*4 + (threadIdx.x >> 6);
    int lane = threadIdx.x & 63;
    int s = esrc[e], d = edst[e];
    int ct = nb[s]*VEt + etype[e];
    int ch = lane*3;
    const u16*   ap = xs1 + (size_t)s*H + ch;
    const u16*   bp = xd1 + (size_t)d*H + ch;
    const float* cp = ctab + (size_t)ct*H + ch;
    float h0, h1, h2;
    { float v = b2f(ap[0])+b2f(bp[0])+cp[0]; h0 = v/(1.f+__expf(-v)); }
    { float v = b2f(ap[1])+b2f(bp[1])+cp[1]; h1 = v/(1.f+__expf(-v)); }
    { float v = b2f(ap[2])+b2f(bp[2])+cp[2]; h2 = v/(1.f+__expf(-v)); }
    float pj[8];
    #pragma unroll
    for(int j = 0; j < 8; j++)
        pj[j] = h0*w2[ch*8+j] + h1*w2[(ch+1)*8+j] + h2*w2[(ch+2)*8+j];
    // split butterfly: 8 outputs over 64 lanes in 10 shuffles
    int b0 = lane & 1, b1 = lane & 2, b2 = lane & 4;
    float v4[4];
    #pragma unroll
    for(int t = 0; t < 4; t++){
        float send = b0 ? pj[t] : pj[t+4];
        float keep = b0 ? pj[t+4] : pj[t];
        v4[t] = keep + __shfl_xor(send, 1);
    }
    float v2[2];
    #pragma unroll
    for(int t = 0; t < 2; t++){
        float send = b1 ? v4[t] : v4[t+2];
        float keep = b1 ? v4[t+2] : v4[t];
        v2[t] = keep + __shfl_xor(send, 2);
    }
    float v1;
    {
        float send = b2 ? v2[0] : v2[1];
        float keep = b2 ? v2[1] : v2[0];
        v1 = keep + __shfl_xor(send, 4);
    }
    v1 += __shfl_xor(v1, 8); v1 += __shfl_xor(v1, 16); v1 += __shfl_xor(v1, 32);
    int j = (lane&1)*4 + (lane&2) + ((lane&4)>>2);
    if(lane < 8) out[(size_t)e*8 + j] = v1 + b2p[j];
}

extern "C" void kernel_launch(void* const* d_in, const int* in_sizes, int n_in,
                              void* d_out, int out_size, void* d_ws, size_t ws_size,
                              hipStream_t stream)
{
    {
        int bad = -1;
        if(n_in != 31) bad = 100;
        else {
            const int chk_idx[9] = {0, 7, 16, 21, 23, 26, 27, 29, 30};
            const int chk_sz [9] = {32*H, NL*HH, NL*3*H, 4*HH, H*8, NE, 2*NE, NN, NBATCH};
            for(int i = 0; i < 9; i++) if(in_sizes[chk_idx[i]] != chk_sz[i]){ bad = chk_idx[i]; break; }
        }
        if(bad >= 0){ k_sentinel<<<1,1,0,stream>>>((float*)d_out, 20000.f + 256.f*bad); return; }
        if(out_size != NN*32 + NE*8){ k_sentinel<<<1,1,0,stream>>>((float*)d_out, 30000.f); return; }
    }

    const float* node_emb = (const float*)d_in[0];
    const float* edge_emb = (const float*)d_in[1];
    const float* time_w1  = (const float*)d_in[2];
    const float* time_b1  = (const float*)d_in[3];
    const float* time_w2  = (const float*)d_in[4];
    const float* time_b2  = (const float*)d_in[5];
    const float* mask_emb = (const float*)d_in[6];
    const float* wq       = (const float*)d_in[7];
    const float* bq       = (const float*)d_in[8];
    const float* wk       = (const float*)d_in[9];
    const float* bk       = (const float*)d_in[10];
    const float* wv       = (const float*)d_in[11];
    const float* bv       = (const float*)d_in[12];
    const float* we       = (const float*)d_in[13];
    const float* wskip    = (const float*)d_in[14];
    const float* bskip    = (const float*)d_in[15];
    const float* wbeta    = (const float*)d_in[16];
    const float* ln_g     = (const float*)d_in[17];
    const float* ln_b     = (const float*)d_in[18];
    const float* now      = (const float*)d_in[19];
    const float* nob      = (const float*)d_in[20];
    const float* ew1      = (const float*)d_in[21];
    const float* eb1      = (const float*)d_in[22];
    const float* ew2      = (const float*)d_in[23];
    const float* eb2      = (const float*)d_in[24];
    const int* node_type  = (const int*)d_in[25];
    const int* edge_type  = (const int*)d_in[26];
    const int* edge_index = (const int*)d_in[27];
    const int* edit_mask  = (const int*)d_in[28];
    const int* node_batch = (const int*)d_in[29];
    const int* t_graph    = (const int*)d_in[30];
    const int* esrc = edge_index;
    const int* edst = edge_index + NE;

    char* wsb = (char*)d_ws;
    size_t off = 0;
    auto take = [&](size_t bytes) -> char* {
        char* r = wsb + off;
        off += (bytes + 255) & ~(size_t)255;
        return r;
    };
    float* tvec = (float*)take((size_t)NBATCH*H*4);
    float* x    = (float*)take((size_t)NN*H*4);
    u16*   xb   = (u16*)  take((size_t)NPAD*H*2);
    float* Q    = (float*)take((size_t)NN*H*4);
    u16*   Kb   = (u16*)  take((size_t)NN*H*2);
    u16*   Vb   = (u16*)  take((size_t)NN*H*2);
    float* XR   = (float*)take((size_t)NN*H*4);
    u16*   xs1  = (u16*)  take((size_t)NN*H*2);
    u16*   xd1  = (u16*)  take((size_t)NN*H*2);
    float* etab = (float*)take((size_t)NL*64*H*4);
    float* ctab = (float*)take((size_t)64*H*4);
    u16*   wt   = (u16*)  take((size_t)18*HH*2);
    int* cnt    = (int*)  take((size_t)(NN+1)*4);
    int* offa   = (int*)  take((size_t)(NN+1)*4);
    int* cur    = (int*)  take((size_t)(NN+1)*4);
    int* ssrc   = (int*)  take((size_t)NE*4);
    int* seix   = (int*)  take((size_t)NE*4);

    if(ws_size < off){
        k_sentinel<<<1,1,0,stream>>>((float*)d_out, 10000.f + (float)(ws_size >> 20));
        return;
    }

    k_transpose<<<18, 256, 0, stream>>>(wq, wk, wv, wskip, ew1, wt);
    k_tvec<<<NBATCH, H, 0, stream>>>(t_graph, time_w1, time_b1, time_w2, time_b2, tvec);
    k_init_x<<<(NN*H + 255)/256, 256, 0, stream>>>(node_emb, mask_emb, tvec, node_type,
                                                   edit_mask, node_batch, x, xb);
    k_zero_i<<<(NN + 255)/256, 256, 0, stream>>>(cnt, NN);
    k_count<<<NE/256, 256, 0, stream>>>(edst, cnt);
    k_scan<<<1, 1024, 0, stream>>>(cnt, offa, cur);
    k_scatter<<<NE/256, 256, 0, stream>>>(esrc, edst, edge_type, node_batch, cur, ssrc, seix);
    k_etab<<<NL*64, H, 0, stream>>>(edge_emb, tvec, we, etab);
    k_ctab<<<64, H, 0, stream>>>(edge_emb, tvec, ew1, eb1, ctab);

    for(int l = 0; l < NL; l++){
        GemmP P;
        P.wt[0] = wt + (size_t)(0  + l)*HH;  P.bias[0] = bq   + (size_t)l*H;  P.out[0] = Q;  P.obf[0] = 0;
        P.wt[1] = wt + (size_t)(4  + l)*HH;  P.bias[1] = bk   + (size_t)l*H;  P.out[1] = Kb; P.obf[1] = 1;
        P.wt[2] = wt + (size_t)(8  + l)*HH;  P.bias[2] = bv   + (size_t)l*H;  P.out[2] = Vb; P.obf[2] = 1;
        P.wt[3] = wt + (size_t)(12 + l)*HH;  P.bias[3] = bskip+ (size_t)l*H;  P.out[3] = XR; P.obf[3] = 0;
        k_gemm<<<dim3(63, 12), 256, 0, stream>>>(xb, P);
        k_attn<<<NN/4, 256, 0, stream>>>(Q, Kb, Vb, XR, etab + (size_t)l*64*H, offa, ssrc, seix,
                                         wbeta + (size_t)l*3*H, ln_g + (size_t)l*H,
                                         ln_b + (size_t)l*H, x, xb);
    }
    {
        GemmP P;
        P.wt[0] = wt + (size_t)16*HH; P.bias[0] = nullptr; P.out[0] = xs1; P.obf[0] = 1;
        P.wt[1] = wt + (size_t)17*HH; P.bias[1] = nullptr; P.out[1] = xd1; P.obf[1] = 1;
        P.wt[2] = P.wt[0]; P.bias[2] = nullptr; P.out[2] = xs1; P.obf[2] = 1;
        P.wt[3] = P.wt[0]; P.bias[3] = nullptr; P.out[3] = xs1; P.obf[3] = 1;
        k_gemm<<<dim3(63, 6), 256, 0, stream>>>(xb, P);
    }
    k_nodeout<<<NN/8, 256, 0, stream>>>(x, now, nob, (float*)d_out);
    k_edgemlp<<<NE/4, 256, 0, stream>>>(esrc, edst, edge_type, node_batch, xs1, xd1, ctab,
                                        ew2, eb2, (float*)d_out + (size_t)NN*32);
}

// Round 10
// 621.305 us; speedup vs baseline: 19.8802x; 1.1928x over previous
//
#include <hip/hip_runtime.h>
#include <hip/hip_bf16.h>
#include <math.h>

#define NN 16000
#define NPAD 16128
#define NE 256000
#define H 192
#define NL 4
#define NBATCH 8
#define VEt 8
#define HH (H*H)
#define EML 16   // edges per wave in k_edgemlp

typedef __hip_bfloat16 bf16;
typedef unsigned short u16;
typedef __attribute__((ext_vector_type(8))) short bfrag_t;
typedef __attribute__((ext_vector_type(4))) float facc_t;

__device__ __forceinline__ bf16 f2b(float v){ return __float2bfloat16(v); }
__device__ __forceinline__ float b2f(u16 v){ bf16 h; *(u16*)&h = v; return __bfloat162float(h); }

__global__ void k_sentinel(float* __restrict__ out, float v){ out[0] = v; }

// ---------------- transpose 18 H×H fp32 weight mats into bf16 [n][k] ----------------
__global__ void k_transpose(const float* __restrict__ wq, const float* __restrict__ wk,
                            const float* __restrict__ wv, const float* __restrict__ wsk,
                            const float* __restrict__ w1, u16* __restrict__ wt){
    int mat = blockIdx.x;
    const float* src;
    if(mat < 4)       src = wq  + (size_t)mat*HH;
    else if(mat < 8)  src = wk  + (size_t)(mat-4)*HH;
    else if(mat < 12) src = wv  + (size_t)(mat-8)*HH;
    else if(mat < 16) src = wsk + (size_t)(mat-12)*HH;
    else              src = w1  + (size_t)(mat-16)*HH;
    u16* dst = wt + (size_t)mat*HH;
    const int slice = HH/8;   // 4608
    int base = blockIdx.y*slice;
    for(int i = base + threadIdx.x; i < base + slice; i += blockDim.x){
        int k = i / H, n = i % H;
        bf16 b = f2b(src[i]);
        dst[n*H + k] = *(u16*)&b;
    }
}

// ---------------- time embedding MLP ----------------
__global__ void k_tvec(const int* __restrict__ tg, const float* __restrict__ w1,
                       const float* __restrict__ b1, const float* __restrict__ w2,
                       const float* __restrict__ b2, float* __restrict__ tvec){
    int b = blockIdx.x, j = threadIdx.x;     // blockDim = 192
    __shared__ float emb[H], h1[H];
    float t = (float)tg[b];
    if(j < 96){
        float fr = __expf(-logf(10000.0f) * (float)j / 96.0f);
        float ang = t * fr;
        emb[j]      = sinf(ang);
        emb[j + 96] = cosf(ang);
    }
    __syncthreads();
    float acc = b1[j];
    for(int k = 0; k < H; k++) acc += emb[k] * w1[k*H + j];
    h1[j] = acc / (1.f + __expf(-acc));
    __syncthreads();
    float acc2 = b2[j];
    for(int k = 0; k < H; k++) acc2 += h1[k] * w2[k*H + j];
    tvec[b*H + j] = acc2;
}

// ---------------- x0 ----------------
__global__ void k_init_x(const float* __restrict__ nemb, const float* __restrict__ memb,
                         const float* __restrict__ tvec, const int* __restrict__ ntype,
                         const int* __restrict__ emask, const int* __restrict__ nbatch,
                         float* __restrict__ x, u16* __restrict__ xb){
    int idx = blockIdx.x*blockDim.x + threadIdx.x;
    if(idx >= NN*H) return;
    int n = idx / H, c = idx % H;
    float v = nemb[(size_t)ntype[n]*H + c] + tvec[nbatch[n]*H + c]
            + memb[(size_t)emask[n]*H + c];
    x[idx] = v;
    bf16 b = f2b(v); xb[idx] = *(u16*)&b;
}

// ---------------- counting sort of edges by dst ----------------
__global__ void k_zero_i(int* __restrict__ p, int n){
    int i = blockIdx.x*blockDim.x + threadIdx.x;
    if(i < n) p[i] = 0;
}
__global__ void k_count(const int* __restrict__ edst, int* __restrict__ cnt){
    int e = blockIdx.x*blockDim.x + threadIdx.x;
    if(e < NE) atomicAdd(&cnt[edst[e]], 1);
}
__global__ __launch_bounds__(1024) void k_scan(const int* __restrict__ cnt,
                                               int* __restrict__ ofs, int* __restrict__ cur){
    __shared__ int wsum[16];
    __shared__ int carry_s;
    int tid = threadIdx.x, lane = tid & 63, w = tid >> 6;
    if(tid == 0) carry_s = 0;
    __syncthreads();
    for(int base = 0; base < NN; base += 1024){
        int idx = base + tid;
        int v = (idx < NN) ? cnt[idx] : 0;
        int sc = v;
        #pragma unroll
        for(int o = 1; o < 64; o <<= 1){
            int t = __shfl_up(sc, o);
            if(lane >= o) sc += t;
        }
        if(lane == 63) wsum[w] = sc;
        __syncthreads();
        if(w == 0){
            int ws = (lane < 16) ? wsum[lane] : 0;
            #pragma unroll
            for(int o = 1; o < 16; o <<= 1){
                int t = __shfl_up(ws, o);
                if(lane >= o) ws += t;
            }
            if(lane < 16) wsum[lane] = ws;
        }
        __syncthreads();
        int wbase = (w > 0) ? wsum[w-1] : 0;
        int c = carry_s;
        int excl = c + wbase + sc - v;
        if(idx < NN){ ofs[idx] = excl; cur[idx] = excl; }
        __syncthreads();
        if(tid == 0) carry_s = c + wsum[15];
        __syncthreads();
    }
    if(threadIdx.x == 0) ofs[NN] = carry_s;
}
__global__ void k_scatter(const int* __restrict__ esrc, const int* __restrict__ edst,
                          const int* __restrict__ etype, const int* __restrict__ nbatch,
                          int* __restrict__ cur, int* __restrict__ ssrc, int* __restrict__ seix){
    int e = blockIdx.x*blockDim.x + threadIdx.x;
    if(e >= NE) return;
    int s = esrc[e], d = edst[e];
    int pos = atomicAdd(&cur[d], 1);
    ssrc[pos] = s;
    seix[pos] = nbatch[s]*VEt + etype[e];
}

// ---------------- e-tables ----------------
__global__ void k_etab(const float* __restrict__ eemb, const float* __restrict__ tvec,
                       const float* __restrict__ we, float* __restrict__ etab){
    int blk = blockIdx.x;                 // l*64 + idx
    int l = blk >> 6, idx = blk & 63, b = idx >> 3, et = idx & 7;
    int c = threadIdx.x;
    __shared__ float a[H];
    a[c] = eemb[et*H + c] + tvec[b*H + c];
    __syncthreads();
    float acc = 0.f;
    const float* w = we + (size_t)l*HH;
    for(int k = 0; k < H; k++) acc += a[k] * w[k*H + c];
    etab[(size_t)blk*H + c] = acc;
}

// ---------------- c-table ----------------
__global__ void k_ctab(const float* __restrict__ eemb, const float* __restrict__ tvec,
                       const float* __restrict__ w1, const float* __restrict__ b1,
                       float* __restrict__ ctab){
    int idx = blockIdx.x, b = idx >> 3, et = idx & 7;
    int c = threadIdx.x;
    __shared__ float a[H];
    a[c] = eemb[et*H + c] + tvec[b*H + c];
    __syncthreads();
    float acc = b1[c];
    for(int k = 0; k < H; k++){
        acc += a[k]          * w1[(size_t)(2*H + k)*H + c];
        acc += tvec[b*H + k] * w1[(size_t)(3*H + k)*H + c];
    }
    ctab[(size_t)idx*H + c] = acc;
}

// ---------------- MFMA GEMM ----------------
struct GemmP {
    const u16* wt[4];
    const float* bias[4];
    void* out[4];
    int obf[4];
};
__global__ __launch_bounds__(256) void k_gemm(const u16* __restrict__ A, GemmP P){
    int oi = blockIdx.y / 3, nt = blockIdx.y % 3;
    const u16* Wt = P.wt[oi];
    const float* bias = P.bias[oi];
    int wave = threadIdx.x >> 6, lane = threadIdx.x & 63;
    int quad = lane >> 4, l16 = lane & 15;
    int m0 = blockIdx.x*256 + wave*64;
    int n0 = nt*64;
    facc_t acc[4][4];
    #pragma unroll
    for(int i = 0; i < 4; i++)
        #pragma unroll
        for(int j = 0; j < 4; j++){ acc[i][j][0]=0.f; acc[i][j][1]=0.f; acc[i][j][2]=0.f; acc[i][j][3]=0.f; }
    #pragma unroll
    for(int kc = 0; kc < 6; kc++){
        int kb = kc*32 + quad*8;
        bfrag_t af[4], bg[4];
        #pragma unroll
        for(int i = 0; i < 4; i++) af[i] = *(const bfrag_t*)(A  + (size_t)(m0 + i*16 + l16)*H + kb);
        #pragma unroll
        for(int j = 0; j < 4; j++) bg[j] = *(const bfrag_t*)(Wt + (size_t)(n0 + j*16 + l16)*H + kb);
        #pragma unroll
        for(int i = 0; i < 4; i++)
            #pragma unroll
            for(int j = 0; j < 4; j++)
                acc[i][j] = __builtin_amdgcn_mfma_f32_16x16x32_bf16(af[i], bg[j], acc[i][j], 0, 0, 0);
    }
    float bv[4];
    #pragma unroll
    for(int j = 0; j < 4; j++) bv[j] = bias ? bias[n0 + j*16 + l16] : 0.f;
    if(P.obf[oi]){
        u16* out = (u16*)P.out[oi];
        #pragma unroll
        for(int i = 0; i < 4; i++){
            int rb = m0 + i*16 + quad*4;
            #pragma unroll
            for(int r = 0; r < 4; r++){
                int row = rb + r;
                if(row < NN){
                    #pragma unroll
                    for(int j = 0; j < 4; j++){
                        bf16 b = f2b(acc[i][j][r] + bv[j]);
                        out[(size_t)row*H + n0 + j*16 + l16] = *(u16*)&b;
                    }
                }
            }
        }
    } else {
        float* out = (float*)P.out[oi];
        #pragma unroll
        for(int i = 0; i < 4; i++){
            int rb = m0 + i*16 + quad*4;
            #pragma unroll
            for(int r = 0; r < 4; r++){
                int row = rb + r;
                if(row < NN){
                    #pragma unroll
                    for(int j = 0; j < 4; j++)
                        out[(size_t)row*H + n0 + j*16 + l16] = acc[i][j][r] + bv[j];
                }
            }
        }
    }
}

// ---------------- fused attention + gate + LN, one wave per node, dual-stream softmax ----------------
__global__ __launch_bounds__(256) void k_attn(
    const float* __restrict__ Q, const u16* __restrict__ Kb,
    const u16* __restrict__ Vb, const float* __restrict__ XR,
    const float* __restrict__ etab, const int* __restrict__ ofs,
    const int* __restrict__ ssrc, const int* __restrict__ seix,
    const float* __restrict__ wb, const float* __restrict__ lng, const float* __restrict__ lnb,
    float* __restrict__ x, u16* __restrict__ xb)
{
    int n = blockIdx.x*4 + (threadIdx.x >> 6);
    int lane = threadIdx.x & 63;
    int ch = lane*3;
    size_t base = (size_t)n*H + ch;
    const float scale = 0.14433756729740646f;   // 1/sqrt(48)
    float q0 = Q[base], q1 = Q[base+1], q2 = Q[base+2];
    int p0 = ofs[n], p1 = ofs[n+1];
    // two independent online-softmax states (even/odd edges) for MLP
    float mA = -3.0e38f, lA = 0.f, aA0 = 0.f, aA1 = 0.f, aA2 = 0.f;
    float mB = -3.0e38f, lB = 0.f, aB0 = 0.f, aB1 = 0.f, aB2 = 0.f;
    int p = p0;
    for(; p + 1 < p1; p += 2){
        int sA = ssrc[p],   eiA = seix[p];
        int sB = ssrc[p+1], eiB = seix[p+1];
        const u16*   kpA = Kb   + (size_t)sA*H  + ch;
        const float* epA = etab + (size_t)eiA*H + ch;
        const u16*   kpB = Kb   + (size_t)sB*H  + ch;
        const float* epB = etab + (size_t)eiB*H + ch;
        float eA0 = epA[0], eA1 = epA[1], eA2 = epA[2];
        float eB0 = epB[0], eB1 = epB[1], eB2 = epB[2];
        float tA = q0*(b2f(kpA[0])+eA0) + q1*(b2f(kpA[1])+eA1) + q2*(b2f(kpA[2])+eA2);
        float tB = q0*(b2f(kpB[0])+eB0) + q1*(b2f(kpB[1])+eB1) + q2*(b2f(kpB[2])+eB2);
        tA += __shfl_xor(tA,1); tB += __shfl_xor(tB,1);
        tA += __shfl_xor(tA,2); tB += __shfl_xor(tB,2);
        tA += __shfl_xor(tA,4); tB += __shfl_xor(tB,4);
        tA += __shfl_xor(tA,8); tB += __shfl_xor(tB,8);
        float scA = tA*scale, scB = tB*scale;
        const u16* vpA = Vb + (size_t)sA*H + ch;
        const u16* vpB = Vb + (size_t)sB*H + ch;
        {
            float mn = fmaxf(mA, scA);
            float corr = __expf(mA - mn), pw = __expf(scA - mn);
            lA  = lA*corr + pw;
            aA0 = aA0*corr + pw*(b2f(vpA[0])+eA0);
            aA1 = aA1*corr + pw*(b2f(vpA[1])+eA1);
            aA2 = aA2*corr + pw*(b2f(vpA[2])+eA2);
            mA = mn;
        }
        {
            float mn = fmaxf(mB, scB);
            float corr = __expf(mB - mn), pw = __expf(scB - mn);
            lB  = lB*corr + pw;
            aB0 = aB0*corr + pw*(b2f(vpB[0])+eB0);
            aB1 = aB1*corr + pw*(b2f(vpB[1])+eB1);
            aB2 = aB2*corr + pw*(b2f(vpB[2])+eB2);
            mB = mn;
        }
    }
    if(p < p1){
        int sA = ssrc[p], eiA = seix[p];
        const u16*   kpA = Kb   + (size_t)sA*H  + ch;
        const float* epA = etab + (size_t)eiA*H + ch;
        float eA0 = epA[0], eA1 = epA[1], eA2 = epA[2];
        float tA = q0*(b2f(kpA[0])+eA0) + q1*(b2f(kpA[1])+eA1) + q2*(b2f(kpA[2])+eA2);
        tA += __shfl_xor(tA,1); tA += __shfl_xor(tA,2); tA += __shfl_xor(tA,4); tA += __shfl_xor(tA,8);
        float scA = tA*scale;
        const u16* vpA = Vb + (size_t)sA*H + ch;
        float mn = fmaxf(mA, scA);
        float corr = __expf(mA - mn), pw = __expf(scA - mn);
        lA  = lA*corr + pw;
        aA0 = aA0*corr + pw*(b2f(vpA[0])+eA0);
        aA1 = aA1*corr + pw*(b2f(vpA[1])+eA1);
        aA2 = aA2*corr + pw*(b2f(vpA[2])+eA2);
        mA = mn;
    }
    // exact merge of the two states
    float mF = fmaxf(mA, mB);
    float cA = __expf(mA - mF), cB = __expf(mB - mF);
    float l  = lA*cA + lB*cB;
    float a0 = aA0*cA + aB0*cB;
    float a1 = aA1*cA + aB1*cB;
    float a2 = aA2*cA + aB2*cB;
    float inv = (p1 > p0) ? 1.f/l : 0.f;
    float o0 = a0*inv, o1 = a1*inv, o2 = a2*inv;
    float xr0 = XR[base], xr1 = XR[base+1], xr2 = XR[base+2];
    float sd = o0*wb[ch]  + o1*wb[ch+1]  + o2*wb[ch+2]
             + xr0*wb[H+ch] + xr1*wb[H+ch+1] + xr2*wb[H+ch+2]
             + (o0-xr0)*wb[2*H+ch] + (o1-xr1)*wb[2*H+ch+1] + (o2-xr2)*wb[2*H+ch+2];
    sd += __shfl_xor(sd,1); sd += __shfl_xor(sd,2); sd += __shfl_xor(sd,4);
    sd += __shfl_xor(sd,8); sd += __shfl_xor(sd,16); sd += __shfl_xor(sd,32);
    float beta = 1.f/(1.f + __expf(-sd));
    float h0 = beta*xr0 + (1.f-beta)*o0;
    float h1 = beta*xr1 + (1.f-beta)*o1;
    float h2 = beta*xr2 + (1.f-beta)*o2;
    float y0 = x[base] + h0, y1 = x[base+1] + h1, y2 = x[base+2] + h2;
    float s3 = y0 + y1 + y2;
    s3 += __shfl_xor(s3,1); s3 += __shfl_xor(s3,2); s3 += __shfl_xor(s3,4);
    s3 += __shfl_xor(s3,8); s3 += __shfl_xor(s3,16); s3 += __shfl_xor(s3,32);
    float mean = s3 * (1.f/H);
    float d0 = y0-mean, d1 = y1-mean, d2 = y2-mean;
    float v3 = d0*d0 + d1*d1 + d2*d2;
    v3 += __shfl_xor(v3,1); v3 += __shfl_xor(v3,2); v3 += __shfl_xor(v3,4);
    v3 += __shfl_xor(v3,8); v3 += __shfl_xor(v3,16); v3 += __shfl_xor(v3,32);
    float rs = rsqrtf(v3*(1.f/H) + 1e-5f);
    float z0 = d0*rs*lng[ch]   + lnb[ch];
    float z1 = d1*rs*lng[ch+1] + lnb[ch+1];
    float z2 = d2*rs*lng[ch+2] + lnb[ch+2];
    x[base] = z0; x[base+1] = z1; x[base+2] = z2;
    bf16 t0 = f2b(z0), t1 = f2b(z1), t2 = f2b(z2);
    xb[base] = *(u16*)&t0; xb[base+1] = *(u16*)&t1; xb[base+2] = *(u16*)&t2;
}

// ---------------- node logits ----------------
__global__ void k_nodeout(const float* __restrict__ x, const float* __restrict__ w,
                          const float* __restrict__ b, float* __restrict__ out){
    int j = threadIdx.x & 31;
    int n = blockIdx.x*8 + (threadIdx.x >> 5);
    float acc = b[j];
    const float* xr = x + (size_t)n*H;
    for(int k = 0; k < H; k++) acc += xr[k] * w[k*32 + j];
    out[(size_t)n*32 + j] = acc;
}

// ---------------- edge logits: 16 edges/wave, w2 hoisted, split-butterfly ----------------
__global__ __launch_bounds__(256) void k_edgemlp(
    const int* __restrict__ esrc, const int* __restrict__ edst, const int* __restrict__ etype,
    const int* __restrict__ nb,
    const u16* __restrict__ xs1, const u16* __restrict__ xd1, const float* __restrict__ ctab,
    const float* __restrict__ w2, const float* __restrict__ b2p, float* __restrict__ out)
{
    int wid = blockIdx.x*4 + (threadIdx.x >> 6);
    int lane = threadIdx.x & 63;
    int ch = lane*3;
    float w2r[3][8];
    #pragma unroll
    for(int t = 0; t < 3; t++)
        #pragma unroll
        for(int j = 0; j < 8; j++) w2r[t][j] = w2[(ch+t)*8 + j];
    int jout = (lane&1)*4 + (lane&2) + ((lane&4)>>2);
    float bo = (lane < 8) ? b2p[jout] : 0.f;
    int b0 = lane & 1, b1 = lane & 2, b2m = lane & 4;
    int e0 = wid*EML;
    for(int e = e0; e < e0 + EML; e++){
        int s = esrc[e], d = edst[e];
        int ct = nb[s]*VEt + etype[e];
        const u16*   ap = xs1 + (size_t)s*H + ch;
        const u16*   bp = xd1 + (size_t)d*H + ch;
        const float* cp = ctab + (size_t)ct*H + ch;
        float h0, h1, h2;
        { float v = b2f(ap[0])+b2f(bp[0])+cp[0]; h0 = v/(1.f+__expf(-v)); }
        { float v = b2f(ap[1])+b2f(bp[1])+cp[1]; h1 = v/(1.f+__expf(-v)); }
        { float v = b2f(ap[2])+b2f(bp[2])+cp[2]; h2 = v/(1.f+__expf(-v)); }
        float pj[8];
        #pragma unroll
        for(int j = 0; j < 8; j++)
            pj[j] = h0*w2r[0][j] + h1*w2r[1][j] + h2*w2r[2][j];
        float v4[4];
        #pragma unroll
        for(int t = 0; t < 4; t++){
            float send = b0 ? pj[t] : pj[t+4];
            float keep = b0 ? pj[t+4] : pj[t];
            v4[t] = keep + __shfl_xor(send, 1);
        }
        float v2[2];
        #pragma unroll
        for(int t = 0; t < 2; t++){
            float send = b1 ? v4[t] : v4[t+2];
            float keep = b1 ? v4[t+2] : v4[t];
            v2[t] = keep + __shfl_xor(send, 2);
        }
        float v1;
        {
            float send = b2m ? v2[0] : v2[1];
            float keep = b2m ? v2[1] : v2[0];
            v1 = keep + __shfl_xor(send, 4);
        }
        v1 += __shfl_xor(v1, 8); v1 += __shfl_xor(v1, 16); v1 += __shfl_xor(v1, 32);
        if(lane < 8) out[(size_t)e*8 + jout] = v1 + bo;
    }
}

extern "C" void kernel_launch(void* const* d_in, const int* in_sizes, int n_in,
                              void* d_out, int out_size, void* d_ws, size_t ws_size,
                              hipStream_t stream)
{
    {
        int bad = -1;
        if(n_in != 31) bad = 100;
        else {
            const int chk_idx[9] = {0, 7, 16, 21, 23, 26, 27, 29, 30};
            const int chk_sz [9] = {32*H, NL*HH, NL*3*H, 4*HH, H*8, NE, 2*NE, NN, NBATCH};
            for(int i = 0; i < 9; i++) if(in_sizes[chk_idx[i]] != chk_sz[i]){ bad = chk_idx[i]; break; }
        }
        if(bad >= 0){ k_sentinel<<<1,1,0,stream>>>((float*)d_out, 20000.f + 256.f*bad); return; }
        if(out_size != NN*32 + NE*8){ k_sentinel<<<1,1,0,stream>>>((float*)d_out, 30000.f); return; }
    }

    const float* node_emb = (const float*)d_in[0];
    const float* edge_emb = (const float*)d_in[1];
    const float* time_w1  = (const float*)d_in[2];
    const float* time_b1  = (const float*)d_in[3];
    const float* time_w2  = (const float*)d_in[4];
    const float* time_b2  = (const float*)d_in[5];
    const float* mask_emb = (const float*)d_in[6];
    const float* wq       = (const float*)d_in[7];
    const float* bq       = (const float*)d_in[8];
    const float* wk       = (const float*)d_in[9];
    const float* bk       = (const float*)d_in[10];
    const float* wv       = (const float*)d_in[11];
    const float* bv       = (const float*)d_in[12];
    const float* we       = (const float*)d_in[13];
    const float* wskip    = (const float*)d_in[14];
    const float* bskip    = (const float*)d_in[15];
    const float* wbeta    = (const float*)d_in[16];
    const float* ln_g     = (const float*)d_in[17];
    const float* ln_b     = (const float*)d_in[18];
    const float* now      = (const float*)d_in[19];
    const float* nob      = (const float*)d_in[20];
    const float* ew1      = (const float*)d_in[21];
    const float* eb1      = (const float*)d_in[22];
    const float* ew2      = (const float*)d_in[23];
    const float* eb2      = (const float*)d_in[24];
    const int* node_type  = (const int*)d_in[25];
    const int* edge_type  = (const int*)d_in[26];
    const int* edge_index = (const int*)d_in[27];
    const int* edit_mask  = (const int*)d_in[28];
    const int* node_batch = (const int*)d_in[29];
    const int* t_graph    = (const int*)d_in[30];
    const int* esrc = edge_index;
    const int* edst = edge_index + NE;

    char* wsb = (char*)d_ws;
    size_t off = 0;
    auto take = [&](size_t bytes) -> char* {
        char* r = wsb + off;
        off += (bytes + 255) & ~(size_t)255;
        return r;
    };
    float* tvec = (float*)take((size_t)NBATCH*H*4);
    float* x    = (float*)take((size_t)NN*H*4);
    u16*   xb   = (u16*)  take((size_t)NPAD*H*2);
    float* Q    = (float*)take((size_t)NN*H*4);
    u16*   Kb   = (u16*)  take((size_t)NN*H*2);
    u16*   Vb   = (u16*)  take((size_t)NN*H*2);
    float* XR   = (float*)take((size_t)NN*H*4);
    u16*   xs1  = (u16*)  take((size_t)NN*H*2);
    u16*   xd1  = (u16*)  take((size_t)NN*H*2);
    float* etab = (float*)take((size_t)NL*64*H*4);
    float* ctab = (float*)take((size_t)64*H*4);
    u16*   wt   = (u16*)  take((size_t)18*HH*2);
    int* cnt    = (int*)  take((size_t)(NN+1)*4);
    int* offa   = (int*)  take((size_t)(NN+1)*4);
    int* cur    = (int*)  take((size_t)(NN+1)*4);
    int* ssrc   = (int*)  take((size_t)NE*4);
    int* seix   = (int*)  take((size_t)NE*4);

    if(ws_size < off){
        k_sentinel<<<1,1,0,stream>>>((float*)d_out, 10000.f + (float)(ws_size >> 20));
        return;
    }

    k_transpose<<<dim3(18, 8), 256, 0, stream>>>(wq, wk, wv, wskip, ew1, wt);
    k_tvec<<<NBATCH, H, 0, stream>>>(t_graph, time_w1, time_b1, time_w2, time_b2, tvec);
    k_init_x<<<(NN*H + 255)/256, 256, 0, stream>>>(node_emb, mask_emb, tvec, node_type,
                                                   edit_mask, node_batch, x, xb);
    k_zero_i<<<(NN + 255)/256, 256, 0, stream>>>(cnt, NN);
    k_count<<<NE/256, 256, 0, stream>>>(edst, cnt);
    k_scan<<<1, 1024, 0, stream>>>(cnt, offa, cur);
    k_scatter<<<NE/256, 256, 0, stream>>>(esrc, edst, edge_type, node_batch, cur, ssrc, seix);
    k_etab<<<NL*64, H, 0, stream>>>(edge_emb, tvec, we, etab);
    k_ctab<<<64, H, 0, stream>>>(edge_emb, tvec, ew1, eb1, ctab);

    for(int l = 0; l < NL; l++){
        GemmP P;
        P.wt[0] = wt + (size_t)(0  + l)*HH;  P.bias[0] = bq   + (size_t)l*H;  P.out[0] = Q;  P.obf[0] = 0;
        P.wt[1] = wt + (size_t)(4  + l)*HH;  P.bias[1] = bk   + (size_t)l*H;  P.out[1] = Kb; P.obf[1] = 1;
        P.wt[2] = wt + (size_t)(8  + l)*HH;  P.bias[2] = bv   + (size_t)l*H;  P.out[2] = Vb; P.obf[2] = 1;
        P.wt[3] = wt + (size_t)(12 + l)*HH;  P.bias[3] = bskip+ (size_t)l*H;  P.out[3] = XR; P.obf[3] = 0;
        k_gemm<<<dim3(63, 12), 256, 0, stream>>>(xb, P);
        k_attn<<<NN/4, 256, 0, stream>>>(Q, Kb, Vb, XR, etab + (size_t)l*64*H, offa, ssrc, seix,
                                         wbeta + (size_t)l*3*H, ln_g + (size_t)l*H,
                                         ln_b + (size_t)l*H, x, xb);
    }
    {
        GemmP P;
        P.wt[0] = wt + (size_t)16*HH; P.bias[0] = nullptr; P.out[0] = xs1; P.obf[0] = 1;
        P.wt[1] = wt + (size_t)17*HH; P.bias[1] = nullptr; P.out[1] = xd1; P.obf[1] = 1;
        P.wt[2] = P.wt[0]; P.bias[2] = nullptr; P.out[2] = xs1; P.obf[2] = 1;
        P.wt[3] = P.wt[0]; P.bias[3] = nullptr; P.out[3] = xs1; P.obf[3] = 1;
        k_gemm<<<dim3(63, 6), 256, 0, stream>>>(xb, P);
    }
    k_nodeout<<<NN/8, 256, 0, stream>>>(x, now, nob, (float*)d_out);
    k_edgemlp<<<NE/(4*EML), 256, 0, stream>>>(esrc, edst, edge_type, node_batch, xs1, xd1, ctab,
                                              ew2, eb2, (float*)d_out + (size_t)NN*32);
}